// Round 2
// baseline (118.165 us; speedup 1.0000x reference)
//
#include <hip/hip_runtime.h>

#define SDIM 256
#define NSEQ 256
#define CDIM 32
#define CZ 128
#define IB 8
#define JB 4

typedef __bf16 bfx8 __attribute__((ext_vector_type(8)));
typedef float fx4 __attribute__((ext_vector_type(4)));
typedef unsigned int u32x2 __attribute__((ext_vector_type(2)));

__device__ __forceinline__ unsigned short f2bf(float f) {
  unsigned int u = __float_as_uint(f);
  u += 0x7fffu + ((u >> 16) & 1u);   // round-to-nearest-even
  return (unsigned short)(u >> 16);
}

__device__ __forceinline__ unsigned int cvtpk(float lo, float hi) {
  unsigned int r;
  asm("v_cvt_pk_bf16_f32 %0, %1, %2" : "=v"(r) : "v"(lo), "v"(hi));
  return r;
}

__device__ __forceinline__ void gload16(const void* g, void* l) {
  __builtin_amdgcn_global_load_lds((const __attribute__((address_space(1))) unsigned int*)g,
                                   (__attribute__((address_space(3))) unsigned int*)l,
                                   16, 0, 0);
}

// ---------------- prep: LN + ab projection (-> bf16, transposed) + W_out -> bf16 (k reordered) ----------------
__global__ __launch_bounds__(256) void opm_prep(
    const float* __restrict__ m_si, const float* __restrict__ gamma, const float* __restrict__ beta,
    const float* __restrict__ Wab, const float* __restrict__ Wout,
    unsigned short* __restrict__ a_t, unsigned short* __restrict__ b_t,
    unsigned short* __restrict__ w2bf)
{
  const int b = blockIdx.x;
  const int t = threadIdx.x;
  if (b < SDIM) {
    __shared__ float wab[2 * CDIM * CDIM];   // 64x32
    __shared__ float gbuf[2 * CDIM];
    for (int k = t; k < 2 * CDIM * CDIM; k += 256) wab[k] = Wab[k];
    if (t < CDIM) { gbuf[t] = gamma[t]; gbuf[CDIM + t] = beta[t]; }
    __syncthreads();

    float x[CDIM];
    const float* src = m_si + (b * NSEQ + t) * CDIM;
#pragma unroll
    for (int c4 = 0; c4 < CDIM / 4; ++c4) {
      fx4 v = *(const fx4*)(src + c4 * 4);
      x[c4 * 4 + 0] = v[0]; x[c4 * 4 + 1] = v[1];
      x[c4 * 4 + 2] = v[2]; x[c4 * 4 + 3] = v[3];
    }
    float mu = 0.f;
#pragma unroll
    for (int c = 0; c < CDIM; ++c) mu += x[c];
    mu *= (1.f / CDIM);
    float var = 0.f;
#pragma unroll
    for (int c = 0; c < CDIM; ++c) { float d = x[c] - mu; var += d * d; }
    var *= (1.f / CDIM);
    const float inv = rsqrtf(var + 1e-5f);
#pragma unroll
    for (int c = 0; c < CDIM; ++c) x[c] = (x[c] - mu) * inv * gbuf[c] + gbuf[CDIM + c];

    for (int dp = 0; dp < 2 * CDIM; ++dp) {
      float s = 0.f;
#pragma unroll
      for (int c = 0; c < CDIM; ++c) s += x[c] * wab[dp * CDIM + c];
      const unsigned short hv = f2bf(s);
      if (dp < CDIM) a_t[(b * CDIM + dp) * NSEQ + t] = hv;
      else           b_t[(b * CDIM + (dp - CDIM)) * NSEQ + t] = hv;
    }
  } else {
    // W_out (z, c*32+d) -> bf16 (z, d*32+c)   [coalesced writes]
    const int idx = (b - SDIM) * 256 + t;      // 0..2047, 64 elems each
    const int flat = idx * 64;
    const int z = flat >> 10;
    const int k0 = flat & 1023;
#pragma unroll 8
    for (int u = 0; u < 64; ++u) {
      const int kp = k0 + u;
      const int d = kp >> 5, c = kp & 31;
      w2bf[flat + u] = f2bf(Wout[z * 1024 + c * CDIM + d]);
    }
  }
}

// ---------------- main: per-block 8x4 (i,j) pairs ----------------
// phase A: O[p][d][c] = sum_n a[i][n][c] * b[j][n][d] / 256   (double-buffered K=32 chunks)
// phase B: z[i,j,z'] = sum_k' W2[z'][k'] * O[p][k'] + b_out   (k' = d*32+c)
__global__ __launch_bounds__(512, 4) void opm_main(
    const unsigned short* __restrict__ a_t, const unsigned short* __restrict__ b_t,
    const unsigned short* __restrict__ w2, const float* __restrict__ bout,
    float* __restrict__ out)
{
  // layout: a0 [0,16K) a1 [16K,32K) b0 [32K,40K) b1 [40K,48K); O overlays [0,64K)
  __shared__ __align__(16) char smem[65536];
  char* o_sh = smem;

  const int tid = threadIdx.x;
  const int lane = tid & 63;
  const int wid = tid >> 6;           // 0..7
  const int g = lane >> 4;            // 0..3
  const int l15 = lane & 15;

  // XCD-aware swizzle (2048 % 8 == 0 -> simple form is bijective).
  // Each XCD gets 256 consecutive work-ids = 4 full i-tiles (a panels L2-resident).
  const int bxr = blockIdx.x;
  const int bx = (bxr & 7) * 256 + (bxr >> 3);
  const int i0 = (bx >> 6) * IB;      // 32 i-tiles
  const int j0 = (bx & 63) * JB;      // 64 j-tiles

  const int jw = wid >> 1;            // wave's j (0..3)
  const int mhalf = wid & 1;          // row half (0..1)
  const int wbase = (tid & ~63) * 16; // wid*64*16, wave-uniform LDS offset unit

  fx4 acc[8][2] = {};

  // ---- staging: chunk = 32 n values. a: 256 rows x 64B, b: 128 rows x 64B.
  // column-slot swizzle: slot cs holds global n-group gs = (cs ^ (row>>1)) & 3
  auto STAGE = [&](int buf, int nc) {
    const int nbase = nc * 32;
    char* ab = smem + buf * 16384;
    char* bb = smem + 32768 + buf * 8192;
#pragma unroll
    for (int pass = 0; pass < 2; ++pass) {          // a: 1024 chunks
      const int q = pass * 512 + tid;
      const int r = q >> 2;
      const int gs = ((q & 3) ^ (r >> 1)) & 3;
      const unsigned short* src = a_t + ((i0 + (r >> 5)) * CDIM + (r & 31)) * NSEQ + nbase + gs * 8;
      gload16(src, ab + pass * 8192 + wbase);
    }
    {                                               // b: 512 chunks
      const int q = tid;
      const int r = q >> 2;
      const int gs = ((q & 3) ^ (r >> 1)) & 3;
      const unsigned short* src = b_t + ((j0 + (r >> 5)) * CDIM + (r & 31)) * NSEQ + nbase + gs * 8;
      gload16(src, bb + wbase);
    }
  };

  auto COMPUTE = [&](int buf) {
    char* ab = smem + buf * 16384;
    char* bb = smem + 32768 + buf * 8192;
    bfx8 bfrag[2];
#pragma unroll
    for (int nt = 0; nt < 2; ++nt) {
      const int rb = jw * 32 + nt * 16 + l15;
      const int cs = (g ^ (rb >> 1)) & 3;
      bfrag[nt] = *(const bfx8*)(bb + rb * 64 + cs * 16);
    }
    __builtin_amdgcn_s_setprio(1);
#pragma unroll
    for (int mi = 0; mi < 8; ++mi) {
      const int rm = mhalf * 128 + mi * 16 + l15;
      const int cs = (g ^ (rm >> 1)) & 3;
      const bfx8 afrag = *(const bfx8*)(ab + rm * 64 + cs * 16);
      acc[mi][0] = __builtin_amdgcn_mfma_f32_16x16x32_bf16(afrag, bfrag[0], acc[mi][0], 0, 0, 0);
      acc[mi][1] = __builtin_amdgcn_mfma_f32_16x16x32_bf16(afrag, bfrag[1], acc[mi][1], 0, 0, 0);
    }
    __builtin_amdgcn_s_setprio(0);
  };

  STAGE(0, 0);
#pragma unroll 2
  for (int t = 0; t < 8; ++t) {
    if (t < 7) {
      STAGE((t + 1) & 1, t + 1);                    // issue next chunk (3 loads/wave)
      asm volatile("s_waitcnt vmcnt(3)" ::: "memory");  // current chunk landed; next stays in flight
    } else {
      asm volatile("s_waitcnt vmcnt(0)" ::: "memory");
    }
    __builtin_amdgcn_s_barrier();
    asm volatile("" ::: "memory");
    COMPUTE(t & 1);
    asm volatile("s_waitcnt lgkmcnt(0)" ::: "memory");  // my ds_reads done before others overwrite
    __builtin_amdgcn_s_barrier();
  }

  // O -> LDS, layout [p][d*64 + c*2] bytes, swizzle ^(((d^p)&7)<<4); scale 1/256
#pragma unroll
  for (int mi = 0; mi < 8; ++mi) {
    const int mt = mhalf * 8 + mi;
    const int p = (mt >> 1) * JB + jw;
    const int c0 = (mt & 1) * 16 + g * 4;
#pragma unroll
    for (int nt = 0; nt < 2; ++nt) {
      const int d = nt * 16 + l15;
      int inner = d * 64 + c0 * 2;
      inner ^= ((d ^ p) & 7) << 4;
      const fx4 s = acc[mi][nt] * 0.00390625f;
      u32x2 v;
      v[0] = cvtpk(s[0], s[1]);
      v[1] = cvtpk(s[2], s[3]);
      *(u32x2*)(o_sh + p * 2048 + inner) = v;
    }
  }
  __syncthreads();

  // phase B: Z[z'][p] = sum_{k'} W2[z'][k'] O[p][k']  (4 split accumulator chains)
  {
    const int mt = wid;               // z' tile
    fx4 a0e = {0.f,0.f,0.f,0.f}, a0o = {0.f,0.f,0.f,0.f};
    fx4 a1e = {0.f,0.f,0.f,0.f}, a1o = {0.f,0.f,0.f,0.f};
    const unsigned short* wrow = w2 + (mt * 16 + l15) * 1024 + g * 8;
    const int pa = l15;
    const int pb = 16 + l15;
#pragma unroll 4
    for (int kp = 0; kp < 16; ++kp) {
      {
        const int ks = kp * 2;
        const bfx8 wf = *(const bfx8*)(wrow + ks * 32);
        const int base = ks * 64 + g * 16;
        const bfx8 oa = *(const bfx8*)(o_sh + pa * 2048 + (base ^ (((ks ^ pa) & 7) << 4)));
        const bfx8 ob = *(const bfx8*)(o_sh + pb * 2048 + (base ^ (((ks ^ pb) & 7) << 4)));
        a0e = __builtin_amdgcn_mfma_f32_16x16x32_bf16(wf, oa, a0e, 0, 0, 0);
        a1e = __builtin_amdgcn_mfma_f32_16x16x32_bf16(wf, ob, a1e, 0, 0, 0);
      }
      {
        const int ks = kp * 2 + 1;
        const bfx8 wf = *(const bfx8*)(wrow + ks * 32);
        const int base = ks * 64 + g * 16;
        const bfx8 oa = *(const bfx8*)(o_sh + pa * 2048 + (base ^ (((ks ^ pa) & 7) << 4)));
        const bfx8 ob = *(const bfx8*)(o_sh + pb * 2048 + (base ^ (((ks ^ pb) & 7) << 4)));
        a0o = __builtin_amdgcn_mfma_f32_16x16x32_bf16(wf, oa, a0o, 0, 0, 0);
        a1o = __builtin_amdgcn_mfma_f32_16x16x32_bf16(wf, ob, a1o, 0, 0, 0);
      }
    }
    const int zp = mt * 16 + g * 4;
    const fx4 bo = *(const fx4*)(bout + zp);
    const fx4 v0 = a0e + a0o + bo;
    const fx4 v1 = a1e + a1o + bo;
    {
      int i = i0 + (pa >> 2), j = j0 + (pa & 3);
      *(fx4*)(out + ((i * SDIM + j) * CZ + zp)) = v0;
    }
    {
      int i = i0 + (pb >> 2), j = j0 + (pb & 3);
      *(fx4*)(out + ((i * SDIM + j) * CZ + zp)) = v1;
    }
  }
}

extern "C" void kernel_launch(void* const* d_in, const int* in_sizes, int n_in,
                              void* d_out, int out_size, void* d_ws, size_t ws_size,
                              hipStream_t stream) {
  const float* m_si  = (const float*)d_in[0];
  const float* gamma = (const float*)d_in[1];
  const float* beta  = (const float*)d_in[2];
  const float* Wab   = (const float*)d_in[3];
  const float* Wout  = (const float*)d_in[4];
  const float* bout  = (const float*)d_in[5];
  float* out = (float*)d_out;

  char* ws = (char*)d_ws;
  unsigned short* a_t = (unsigned short*)ws;                    // 4 MB
  unsigned short* b_t = (unsigned short*)(ws + (4u << 20));     // 4 MB
  unsigned short* w2  = (unsigned short*)(ws + (8u << 20));     // 256 KB

  opm_prep<<<dim3(SDIM + 8), dim3(256), 0, stream>>>(m_si, gamma, beta, Wab, Wout, a_t, b_t, w2);
  opm_main<<<dim3(2048), dim3(512), 0, stream>>>(a_t, b_t, w2, bout, out);
}